// Round 8
// baseline (81.042 us; speedup 1.0000x reference)
//
#include <hip/hip_runtime.h>
#include <math.h>

// Chamfer distance via MFMA, pred/gt (4,8192,3) fp32 -> scalar.
// d(q,g) = s_q + s_g - 2 q.g as one K=16 fp16 MFMA dot (2-way fp16 split per
// coord; products exact in fp32 accum):
//   q row:  {xh,xh,xl,xl,yh,yh,yl,yl | zh,zh,zl,zl, 1, 1, sh,sl}
//   t row:  {Xh,Xl,Xh,Xl,Yh,Yl,Yh,Yl | Zh,Zl,Zh,Zl,sh,sl, 1, 1}   (X=-2x etc)
// A = 32 targets, B = 32 queries, v_mfma_f32_32x32x16_f16 (layout verified R5/R6;
// packed-buffer layout + indexing harness-verified R8, absmax 0.0).
// R15: R13/R14's inline-asm v_min3 fold CHANGED RESULTS (R12 fminf: absmax 0.0;
// R13 MIN3: 4.88e-4; R14 MIN3 w/o result-pin: 3.1e-2 bf16 FAIL) -- inline-asm
// consumers of MFMA dst registers bypass the compiler's MFMA->VALU hazard
// handling. It was also timing-neutral (R13). Reverted to R11's pure-fminf
// depth-1 vacc fold (absmax 0.0, Round 4). This round actually tests R14's
// hypothesis: no LDS, no barriers, no per-block repack -- A-frags read
// DIRECTLY from the L2-resident 1.5MB packed buffer (lane-contiguous dwordx4,
// addressing identical to R8's verified global_load_lds source).

typedef _Float16 half8 __attribute__((ext_vector_type(8)));
typedef float f32x16 __attribute__((ext_vector_type(16)));

#define NPTS   8192
#define CLOUD  32768              // 4 batches * 8192
#define NSPLIT 4                  // target splits per cloud
#define NQ_TOT 65536              // 2 dirs * 32768 queries

// workspace layout:
//   [0, 1M)     pmin   [split][query] partial mins
//   [1M, 3M)    packed_t  [dir][b][k>>5][h][k&31]  half8 (A-frag order)
//   [3M, 5M)    packed_q  [dir][b][q][h]           half8
#define PT_OFF (1 * 1024 * 1024)
#define PQ_OFF (3 * 1024 * 1024)

__device__ __forceinline__ void split2(float v, _Float16& h, _Float16& l) {
  h = (_Float16)v; l = (_Float16)(v - (float)h);
}

// Pack every point exactly once: query-form (cloud==dir) + target-form
// (serving dir==cloud^1). 65536 threads. Layout verified in R8 (absmax 0.0).
__global__ __launch_bounds__(256) void pack_points(
    const float* __restrict__ pred, const float* __restrict__ gt,
    half8* __restrict__ pt, half8* __restrict__ pq, float* __restrict__ out) {
  int id = blockIdx.x * 256 + threadIdx.x;     // 0..65535
  if (id == 0) out[0] = 0.f;                    // kernels run in stream order
  int cloud = id >> 15;                         // 0 = pred, 1 = gt
  int idx = id & (CLOUD - 1);                   // b*8192 + k
  const float* src = cloud ? gt : pred;
  float x = src[3 * idx], y = src[3 * idx + 1], z = src[3 * idx + 2];
  float s = x * x + y * y + z * z;
  _Float16 xh, xl, yh, yl, zh, zl, sh, sl;
  split2(x, xh, xl); split2(y, yh, yl); split2(z, zh, zl); split2(s, sh, sl);
  _Float16 one = (_Float16)1.0f;

  // query form: rows consumed as bq = pqb[q*2 + (lane>>5)]
  size_t qbase = (size_t)cloud * 65536 + (size_t)idx * 2;
  pq[qbase]     = (half8){xh, xh, xl, xl, yh, yh, yl, yl};
  pq[qbase + 1] = (half8){zh, zh, zl, zl, one, one, sh, sl};

  // target form, A-frag-linear: tile (idx>>5), frag row h at +h*32, pt idx&31
  _Float16 Xh = (_Float16)(-2.f * (float)xh), Xl = (_Float16)(-2.f * (float)xl);
  _Float16 Yh = (_Float16)(-2.f * (float)yh), Yl = (_Float16)(-2.f * (float)yl);
  _Float16 Zh = (_Float16)(-2.f * (float)zh), Zl = (_Float16)(-2.f * (float)zl);
  size_t tbase = (size_t)(cloud ^ 1) * 65536 + (size_t)(idx >> 5) * 64 + (idx & 31);
  pt[tbase]      = (half8){Xh, Xl, Xh, Xl, Yh, Yl, Yh, Yl};
  pt[tbase + 32] = (half8){Zh, Zl, Zh, Zl, sh, sl, one, one};
}

__global__ __launch_bounds__(256, 4) void chamfer_mfma(
    const half8* __restrict__ pt, const half8* __restrict__ pq,
    float* __restrict__ pmin) {
  int bid = blockIdx.x;            // 1024 = dir(2) * b(4) * qblk(32) * split(4)
  int split = bid & 3;
  int qblk  = (bid >> 2) & 31;
  int b     = (bid >> 7) & 3;
  int dir   = bid >> 9;            // 0: q=pred t=gt ; 1: q=gt t=pred
  int t = threadIdx.x, lane = t & 63, wave = t >> 6;
  int hi = lane >> 5, ql = lane & 31;

  // ---- queries: pre-packed, two b128 loads per lane (R8-verified) ----
  int qstart = qblk * 256 + wave * 64;
  const half8* pqb = pq + (size_t)dir * 65536 + (size_t)b * 16384 + (size_t)qstart * 2;
  half8 bq0 = pqb[2 * ql + hi];
  half8 bq1 = pqb[2 * (ql + 32) + hi];

  // ---- targets: A-frags straight from L2-resident packed buffer ----
  // this block's 2048 targets = 64 A-tiles of 64 half8 each
  const half8* ta = pt + (size_t)dir * 65536 + (size_t)b * 16384
                       + (size_t)split * 4096;

  // persistent vector-min accumulators: depth-1 fminf folds (absmax 0.0, R11)
  float vacc0[8], vacc1[8];
  #pragma unroll
  for (int j = 0; j < 8; ++j) { vacc0[j] = INFINITY; vacc1[j] = INFINITY; }

  f32x16 zero = {};
  #pragma unroll 4
  for (int g = 0; g < 64; ++g) {
    half8 a = ta[g * 64 + lane];     // global_load_dwordx4, 1KB/wave, L2-hit
    f32x16 d0 = __builtin_amdgcn_mfma_f32_32x32x16_f16(a, bq0, zero, 0, 0, 0);
    f32x16 d1 = __builtin_amdgcn_mfma_f32_32x32x16_f16(a, bq1, zero, 0, 0, 0);
    #pragma unroll
    for (int j = 0; j < 8; ++j) {    // 16 independent depth-1 min chains
      vacc0[j] = fminf(fminf(vacc0[j], d0[2 * j]), d0[2 * j + 1]);
      vacc1[j] = fminf(fminf(vacc1[j], d1[2 * j]), d1[2 * j + 1]);
    }
  }
  // end-of-wave tree fold (once, amortized over 128 MFMAs)
  float a0 = fminf(fminf(vacc0[0], vacc0[1]), vacc0[2]);
  float a1 = fminf(fminf(vacc0[3], vacc0[4]), vacc0[5]);
  float a2 = fminf(vacc0[6], vacc0[7]);
  float m0 = fminf(fminf(a0, a1), a2);
  float b0 = fminf(fminf(vacc1[0], vacc1[1]), vacc1[2]);
  float b1 = fminf(fminf(vacc1[3], vacc1[4]), vacc1[5]);
  float b2 = fminf(vacc1[6], vacc1[7]);
  float m1 = fminf(fminf(b0, b1), b2);
  // lane^32 holds the other 16 target rows of each tile
  m0 = fminf(m0, __shfl_xor(m0, 32, 64));
  m1 = fminf(m1, __shfl_xor(m1, 32, 64));

  // ---- plain coalesced store of this split's partial mins ----
  if (lane < 32) {
    size_t qi = (size_t)dir * 32768 + (size_t)b * NPTS + qstart + ql;
    pmin[(size_t)split * NQ_TOT + qi]      = m0;
    pmin[(size_t)split * NQ_TOT + qi + 32] = m1;
  }
}

__global__ __launch_bounds__(256) void reduce_kernel(
    const float* __restrict__ pmin, float* __restrict__ out) {
  __shared__ float wsum[4];
  float acc = 0.f;
  for (int i = blockIdx.x * 256 + threadIdx.x; i < NQ_TOT; i += 64 * 256) {
    float v = pmin[i];
    #pragma unroll
    for (int s = 1; s < NSPLIT; ++s) v = fminf(v, pmin[(size_t)s * NQ_TOT + i]);
    acc += fmaxf(v, 0.f);
  }
  acc *= (1.0f / 32768.0f);
  #pragma unroll
  for (int off = 32; off > 0; off >>= 1) acc += __shfl_down(acc, off, 64);
  int wid = threadIdx.x >> 6;
  if ((threadIdx.x & 63) == 0) wsum[wid] = acc;
  __syncthreads();
  if (threadIdx.x == 0) atomicAdd(out, wsum[0] + wsum[1] + wsum[2] + wsum[3]);
}

extern "C" void kernel_launch(void* const* d_in, const int* in_sizes, int n_in,
                              void* d_out, int out_size, void* d_ws, size_t ws_size,
                              hipStream_t stream) {
  const float* pred = (const float*)d_in[0];
  const float* gt   = (const float*)d_in[1];
  float* out = (float*)d_out;
  float* pmin = (float*)d_ws;                             // 1 MB partial mins
  half8* pt = (half8*)((char*)d_ws + PT_OFF);             // 2 MB packed targets
  half8* pq = (half8*)((char*)d_ws + PQ_OFF);             // 2 MB packed queries

  pack_points<<<256, 256, 0, stream>>>(pred, gt, pt, pq, out);
  chamfer_mfma<<<1024, 256, 0, stream>>>(pt, pq, pmin);
  reduce_kernel<<<64, 256, 0, stream>>>(pmin, out);
}

// Round 10
// 79.889 us; speedup vs baseline: 1.0144x; 1.0144x over previous
//
#include <hip/hip_runtime.h>
#include <math.h>

// Chamfer distance via MFMA, pred/gt (4,8192,3) fp32 -> scalar.
// d(q,g) = s_q + s_g - 2 q.g as one K=16 fp16 MFMA dot (2-way fp16 split per
// coord; products exact in fp32 accum):
//   q row:  {xh,xh,xl,xl,yh,yh,yl,yl | zh,zh,zl,zl, 1, 1, sh,sl}
//   t row:  {Xh,Xl,Xh,Xl,Yh,Yl,Yh,Yl | Zh,Zl,Zh,Zl,sh,sl, 1, 1}   (X=-2x etc)
// A = 32 targets, B = 32 queries, v_mfma_f32_32x32x16_f16 (layout verified R5/R6).
// R17: float_control unsupported (R16 compile fail). Same theory -- fminf on
// MFMA results pays IEEE canonicalize (v_max x,x per operand, ~64-96 VALU/
// g-iter; matches R9's measured 106 and the R11/R12/R13 neutrality) -- new
// escape: INTEGER-DOMAIN MIN. Signed-int compare on float bits is order-exact
// for non-negatives; our distances are >= -1e-6, and the reduce's fmaxf(v,0)
// clamp makes int-min BIT-EQUIVALENT to float-min end-to-end. smin has no
// canonicalize/NaN baggage and fuses to v_min3_i32; __float_as_int is a free
// bitcast. Fold = exactly 16 v_min3_i32/g-iter, intrinsic consumers only
// (no inline-asm reads of MFMA results -- R13/R14 hazard class avoided;
// only asm is R12's proven no-op VGPR pin). Rest = R12 structure verbatim:
// NSPLIT=4, 1024 blocks = 4 blocks/CU, LDS 16KB A-frag-linear, (256,4).

typedef _Float16 half8 __attribute__((ext_vector_type(8)));
typedef float f32x16 __attribute__((ext_vector_type(16)));

#define NPTS   8192
#define TT     512                // targets per LDS chunk (16 KB)
#define NSPLIT 4                  // target splits per cloud
#define SCH    4                  // chunks per split (2048 targets)
#define NQ_TOT 65536              // 2 dirs * 32768 queries

__device__ __forceinline__ int imin(int a, int b) { return a < b ? a : b; }

__device__ __forceinline__ void split2(float v, _Float16& h, _Float16& l) {
  h = (_Float16)v; l = (_Float16)(v - (float)h);
}

__device__ __forceinline__ void pack_target(float x, float y, float z,
                                            half8& fa, half8& fb) {
  float s = x * x + y * y + z * z;
  _Float16 xh, xl, yh, yl, zh, zl, sh, sl;
  split2(x, xh, xl); split2(y, yh, yl); split2(z, zh, zl); split2(s, sh, sl);
  _Float16 one = (_Float16)1.0f;
  _Float16 Xh = (_Float16)(-2.f * (float)xh), Xl = (_Float16)(-2.f * (float)xl);
  _Float16 Yh = (_Float16)(-2.f * (float)yh), Yl = (_Float16)(-2.f * (float)yl);
  _Float16 Zh = (_Float16)(-2.f * (float)zh), Zl = (_Float16)(-2.f * (float)zl);
  fa = (half8){Xh, Xl, Xh, Xl, Yh, Yl, Yh, Yl};
  fb = (half8){Zh, Zl, Zh, Zl, sh, sl, one, one};
}

__global__ __launch_bounds__(256, 4) void chamfer_mfma(
    const float* __restrict__ pred, const float* __restrict__ gt,
    float* __restrict__ pmin, float* __restrict__ out) {
  __shared__ __align__(16) half8 lds[TT * 2];   // 16 KB, A-frag-linear
  int bid = blockIdx.x;            // 1024 = dir(2) * b(4) * qblk(32) * split(4)
  int split = bid & 3;
  int qblk  = (bid >> 2) & 31;
  int b     = (bid >> 7) & 3;
  int dir   = bid >> 9;            // 0: q=pred t=gt ; 1: q=gt t=pred
  const float* qsrc = dir ? gt : pred;
  const float* tsrc = dir ? pred : gt;
  int t = threadIdx.x, lane = t & 63, wave = t >> 6, ql = lane & 31;
  if (bid == 0 && t == 0) out[0] = 0.f;   // reduce runs strictly after

  // ---- queries: wave handles 64 queries as two B-frags (layout verified) ----
  int qstart = qblk * 256 + wave * 64;
  const float* qb = qsrc + (size_t)(b * NPTS + qstart) * 3;
  float q0x = qb[3 * ql],        q0y = qb[3 * ql + 1],        q0z = qb[3 * ql + 2];
  float q1x = qb[3 * (ql + 32)], q1y = qb[3 * (ql + 32) + 1], q1z = qb[3 * (ql + 32) + 2];
  half8 bq0, bq1;
  {
    float s0 = q0x * q0x + q0y * q0y + q0z * q0z;
    float s1 = q1x * q1x + q1y * q1y + q1z * q1z;
    _Float16 x0h, x0l, y0h, y0l, z0h, z0l, s0h, s0l;
    _Float16 x1h, x1l, y1h, y1l, z1h, z1l, s1h, s1l;
    split2(q0x, x0h, x0l); split2(q0y, y0h, y0l); split2(q0z, z0h, z0l); split2(s0, s0h, s0l);
    split2(q1x, x1h, x1l); split2(q1y, y1h, y1l); split2(q1z, z1h, z1l); split2(s1, s1h, s1l);
    _Float16 one = (_Float16)1.0f;
    bq0 = (lane < 32) ? (half8){x0h, x0h, x0l, x0l, y0h, y0h, y0l, y0l}
                      : (half8){z0h, z0h, z0l, z0l, one, one, s0h, s0l};
    bq1 = (lane < 32) ? (half8){x1h, x1h, x1l, x1l, y1h, y1h, y1l, y1l}
                      : (half8){z1h, z1h, z1l, z1l, one, one, s1h, s1l};
  }

  // ---- target loop: SCH chunks of this split, reg-prefetch double-buffer ----
  const float* tb = tsrc + (size_t)(b * NPTS + split * (SCH * TT)) * 3;
  float p0x, p0y, p0z, p1x, p1y, p1z;
  {
    const float* s0 = tb + (size_t)t * 3;
    const float* s1 = tb + (size_t)(t + 256) * 3;
    p0x = s0[0]; p0y = s0[1]; p0z = s0[2];
    p1x = s1[0]; p1y = s1[1]; p1z = s1[2];
  }

  // integer-domain min accumulators (bits of 1e30f; see header note)
  int iacc0[8], iacc1[8];
  const int INIT = __float_as_int(1e30f);
  #pragma unroll
  for (int j = 0; j < 8; ++j) { iacc0[j] = INIT; iacc1[j] = INIT; }

  f32x16 zero = {};
  for (int tc = 0; tc < SCH; ++tc) {
    half8 f0a, f0b, f1a, f1b;
    pack_target(p0x, p0y, p0z, f0a, f0b);
    pack_target(p1x, p1y, p1z, f1a, f1b);
    if (tc) __syncthreads();           // prior chunk's reads done before overwrite
    // A-frag-linear: point k -> lds[(k>>5)*64 + (k&31)] (+32 for frag row 1)
    int base0 = (t >> 5) * 64 + (t & 31);
    lds[base0]            = f0a;
    lds[base0 + 32]       = f0b;
    lds[base0 + 512]      = f1a;       // point t+256 lands 8 tiles later
    lds[base0 + 512 + 32] = f1b;
    if (tc + 1 < SCH) {                // prefetch next chunk during compute
      const float* s0 = tb + (size_t)((tc + 1) * TT + t) * 3;
      const float* s1 = tb + (size_t)((tc + 1) * TT + t + 256) * 3;
      p0x = s0[0]; p0y = s0[1]; p0z = s0[2];
      p1x = s1[0]; p1y = s1[1]; p1z = s1[2];
    }
    __syncthreads();

    #pragma unroll 4
    for (int g = 0; g < TT / 32; ++g) {
      half8 a = lds[g * 64 + lane];    // lane-contiguous: zero bank conflicts
      f32x16 d0 = __builtin_amdgcn_mfma_f32_32x32x16_f16(a, bq0, zero, 0, 0, 0);
      f32x16 d1 = __builtin_amdgcn_mfma_f32_32x32x16_f16(a, bq1, zero, 0, 0, 0);
      asm("" : "+v"(d0), "+v"(d1));    // no-op pin: keep results in ArchVGPRs
      #pragma unroll
      for (int j = 0; j < 8; ++j) {    // 16x v_min3_i32: no canonicalize, no NaN
        iacc0[j] = imin(iacc0[j],
                        imin(__float_as_int(d0[2 * j]), __float_as_int(d0[2 * j + 1])));
        iacc1[j] = imin(iacc1[j],
                        imin(__float_as_int(d1[2 * j]), __float_as_int(d1[2 * j + 1])));
      }
    }
  }
  // end-of-wave tree fold in int domain (once, amortized over 128 MFMAs)
  int ia0 = imin(imin(iacc0[0], iacc0[1]), imin(iacc0[2], iacc0[3]));
  int ia1 = imin(imin(iacc0[4], iacc0[5]), imin(iacc0[6], iacc0[7]));
  int ib0 = imin(imin(iacc1[0], iacc1[1]), imin(iacc1[2], iacc1[3]));
  int ib1 = imin(imin(iacc1[4], iacc1[5]), imin(iacc1[6], iacc1[7]));
  float m0 = __int_as_float(imin(ia0, ia1));
  float m1 = __int_as_float(imin(ib0, ib1));
  // lane^32 holds the other 16 target rows of each tile
  m0 = fminf(m0, __shfl_xor(m0, 32, 64));
  m1 = fminf(m1, __shfl_xor(m1, 32, 64));

  // ---- plain coalesced store of this split's partial mins ----
  if (lane < 32) {
    size_t qi = (size_t)dir * 32768 + (size_t)b * NPTS + qstart + ql;
    pmin[(size_t)split * NQ_TOT + qi]      = m0;
    pmin[(size_t)split * NQ_TOT + qi + 32] = m1;
  }
}

__global__ __launch_bounds__(256) void reduce_kernel(
    const float* __restrict__ pmin, float* __restrict__ out) {
  __shared__ float wsum[4];
  float acc = 0.f;
  for (int i = blockIdx.x * 256 + threadIdx.x; i < NQ_TOT; i += 64 * 256) {
    float v = pmin[i];
    #pragma unroll
    for (int s = 1; s < NSPLIT; ++s) v = fminf(v, pmin[(size_t)s * NQ_TOT + i]);
    acc += fmaxf(v, 0.f);   // clamp: makes int-domain min exactly float-min
  }
  acc *= (1.0f / 32768.0f);
  #pragma unroll
  for (int off = 32; off > 0; off >>= 1) acc += __shfl_down(acc, off, 64);
  int wid = threadIdx.x >> 6;
  if ((threadIdx.x & 63) == 0) wsum[wid] = acc;
  __syncthreads();
  if (threadIdx.x == 0) atomicAdd(out, wsum[0] + wsum[1] + wsum[2] + wsum[3]);
}

extern "C" void kernel_launch(void* const* d_in, const int* in_sizes, int n_in,
                              void* d_out, int out_size, void* d_ws, size_t ws_size,
                              hipStream_t stream) {
  const float* pred = (const float*)d_in[0];
  const float* gt   = (const float*)d_in[1];
  float* out = (float*)d_out;
  float* pmin = (float*)d_ws;         // 4 * 65536 * 4 B = 1 MB partial mins

  chamfer_mfma<<<1024, 256, 0, stream>>>(pred, gt, pmin, out);
  reduce_kernel<<<64, 256, 0, stream>>>(pmin, out);
}

// Round 11
// 76.280 us; speedup vs baseline: 1.0624x; 1.0473x over previous
//
#include <hip/hip_runtime.h>
#include <math.h>

// Chamfer distance via MFMA, pred/gt (4,8192,3) fp32 -> scalar.
// d(q,g) = s_q + s_g - 2 q.g as one K=16 fp16 MFMA dot (2-way fp16 split per
// coord; products exact in fp32 accum):
//   q row:  {xh,xh,xl,xl,yh,yh,yl,yl | zh,zh,zl,zl, 1, 1, sh,sl}
//   t row:  {Xh,Xl,Xh,Xl,Yh,Yl,Yh,Yl | Zh,Zl,Zh,Zl,sh,sl, 1, 1}   (X=-2x etc)
// A = 32 targets, B = 32 queries, v_mfma_f32_32x32x16_f16 (layout verified R5/R6).
// R18: fold-codegen hypothesis class fully falsified (R11/R12/R13/R17: four
// fold implementations, same ~24-31us chamfer). Remaining fit to all data:
// cost scales with G-ITERATION COUNT (serial 532 cyc/g-iter at 1 wave [R9],
// ~225 cyc/slot at 4-8 waves = ~50% packing), not with MFMA or fold count.
// Lever: 4 B-frags per wave (128 queries) -> 1 ds_read feeds 4 MFMAs;
// g-iters halve 262144->131072, ds_reads halve, loop/wait overhead per MFMA
// halves; MFMA + fold totals unchanged. VGPR fitted to (256,4)=128 by folding
// d0/d1 before issuing d2/d3 (peak d-live 32; ~123 total).
// Geometry: 1024 blocks = dir(2)*b(4)*qblk(16)*split(8), 512 q x 1024 t per
// block, SCH=2 chunks of TT=512, LDS 16KB single-buf, R12 staging verbatim.

typedef _Float16 half8 __attribute__((ext_vector_type(8)));
typedef float f32x16 __attribute__((ext_vector_type(16)));

#define NPTS   8192
#define TT     512                // targets per LDS chunk (16 KB)
#define NSPLIT 8                  // target splits per cloud
#define SCH    2                  // chunks per split (1024 targets)
#define NQ_TOT 65536              // 2 dirs * 32768 queries

__device__ __forceinline__ void split2(float v, _Float16& h, _Float16& l) {
  h = (_Float16)v; l = (_Float16)(v - (float)h);
}

__device__ __forceinline__ void pack_target(float x, float y, float z,
                                            half8& fa, half8& fb) {
  float s = x * x + y * y + z * z;
  _Float16 xh, xl, yh, yl, zh, zl, sh, sl;
  split2(x, xh, xl); split2(y, yh, yl); split2(z, zh, zl); split2(s, sh, sl);
  _Float16 one = (_Float16)1.0f;
  _Float16 Xh = (_Float16)(-2.f * (float)xh), Xl = (_Float16)(-2.f * (float)xl);
  _Float16 Yh = (_Float16)(-2.f * (float)yh), Yl = (_Float16)(-2.f * (float)yl);
  _Float16 Zh = (_Float16)(-2.f * (float)zh), Zl = (_Float16)(-2.f * (float)zl);
  fa = (half8){Xh, Xl, Xh, Xl, Yh, Yl, Yh, Yl};
  fb = (half8){Zh, Zl, Zh, Zl, sh, sl, one, one};
}

// build one query B-frag from a point (layout verified R5/R6)
__device__ __forceinline__ half8 pack_query(float x, float y, float z, bool lo) {
  float s = x * x + y * y + z * z;
  _Float16 xh, xl, yh, yl, zh, zl, sh, sl;
  split2(x, xh, xl); split2(y, yh, yl); split2(z, zh, zl); split2(s, sh, sl);
  _Float16 one = (_Float16)1.0f;
  return lo ? (half8){xh, xh, xl, xl, yh, yh, yl, yl}
            : (half8){zh, zh, zl, zl, one, one, sh, sl};
}

__global__ __launch_bounds__(256, 4) void chamfer_mfma(
    const float* __restrict__ pred, const float* __restrict__ gt,
    float* __restrict__ pmin, float* __restrict__ out) {
  __shared__ __align__(16) half8 lds[TT * 2];   // 16 KB, A-frag-linear
  int bid = blockIdx.x;            // 1024 = dir(2) * b(4) * qblk(16) * split(8)
  int split = bid & 7;
  int qblk  = (bid >> 3) & 15;
  int b     = (bid >> 7) & 3;
  int dir   = bid >> 9;            // 0: q=pred t=gt ; 1: q=gt t=pred
  const float* qsrc = dir ? gt : pred;
  const float* tsrc = dir ? pred : gt;
  int t = threadIdx.x, lane = t & 63, wave = t >> 6, ql = lane & 31;
  bool lo = (lane < 32);
  if (bid == 0 && t == 0) out[0] = 0.f;   // reduce runs strictly after

  // ---- queries: wave handles 128 queries as four B-frags ----
  int qstart = qblk * 512 + wave * 128;
  const float* qb = qsrc + (size_t)(b * NPTS + qstart) * 3;
  half8 bq0, bq1, bq2, bq3;
  {
    int i0 = 3 * ql, i1 = 3 * (ql + 32), i2 = 3 * (ql + 64), i3 = 3 * (ql + 96);
    bq0 = pack_query(qb[i0], qb[i0 + 1], qb[i0 + 2], lo);
    bq1 = pack_query(qb[i1], qb[i1 + 1], qb[i1 + 2], lo);
    bq2 = pack_query(qb[i2], qb[i2 + 1], qb[i2 + 2], lo);
    bq3 = pack_query(qb[i3], qb[i3 + 1], qb[i3 + 2], lo);
  }

  // ---- target loop: SCH chunks of this split, reg-prefetch double-buffer ----
  const float* tb = tsrc + (size_t)(b * NPTS + split * (SCH * TT)) * 3;
  float p0x, p0y, p0z, p1x, p1y, p1z;
  {
    const float* s0 = tb + (size_t)t * 3;
    const float* s1 = tb + (size_t)(t + 256) * 3;
    p0x = s0[0]; p0y = s0[1]; p0z = s0[2];
    p1x = s1[0]; p1y = s1[1]; p1z = s1[2];
  }

  // persistent vector-min accumulators: depth-1 fminf folds (R12 pedigree)
  float vacc0[8], vacc1[8], vacc2[8], vacc3[8];
  #pragma unroll
  for (int j = 0; j < 8; ++j) {
    vacc0[j] = INFINITY; vacc1[j] = INFINITY;
    vacc2[j] = INFINITY; vacc3[j] = INFINITY;
  }

  f32x16 zero = {};
  for (int tc = 0; tc < SCH; ++tc) {
    half8 f0a, f0b, f1a, f1b;
    pack_target(p0x, p0y, p0z, f0a, f0b);
    pack_target(p1x, p1y, p1z, f1a, f1b);
    if (tc) __syncthreads();           // prior chunk's reads done before overwrite
    // A-frag-linear: point k -> lds[(k>>5)*64 + (k&31)] (+32 for frag row 1)
    int base0 = (t >> 5) * 64 + (t & 31);
    lds[base0]            = f0a;
    lds[base0 + 32]       = f0b;
    lds[base0 + 512]      = f1a;       // point t+256 lands 8 tiles later
    lds[base0 + 512 + 32] = f1b;
    if (tc + 1 < SCH) {                // prefetch next chunk during compute
      const float* s0 = tb + (size_t)((tc + 1) * TT + t) * 3;
      const float* s1 = tb + (size_t)((tc + 1) * TT + t + 256) * 3;
      p0x = s0[0]; p0y = s0[1]; p0z = s0[2];
      p1x = s1[0]; p1y = s1[1]; p1z = s1[2];
    }
    __syncthreads();

    #pragma unroll 2
    for (int g = 0; g < TT / 32; ++g) {
      half8 a = lds[g * 64 + lane];    // 1 ds_read feeds 4 MFMAs
      // pair 1: compute + fold (keeps peak d-live at 32 regs)
      f32x16 d0 = __builtin_amdgcn_mfma_f32_32x32x16_f16(a, bq0, zero, 0, 0, 0);
      f32x16 d1 = __builtin_amdgcn_mfma_f32_32x32x16_f16(a, bq1, zero, 0, 0, 0);
      asm("" : "+v"(d0), "+v"(d1));    // no-op pin: results in ArchVGPRs
      #pragma unroll
      for (int j = 0; j < 8; ++j) {
        vacc0[j] = fminf(fminf(vacc0[j], d0[2 * j]), d0[2 * j + 1]);
        vacc1[j] = fminf(fminf(vacc1[j], d1[2 * j]), d1[2 * j + 1]);
      }
      // pair 2
      f32x16 d2 = __builtin_amdgcn_mfma_f32_32x32x16_f16(a, bq2, zero, 0, 0, 0);
      f32x16 d3 = __builtin_amdgcn_mfma_f32_32x32x16_f16(a, bq3, zero, 0, 0, 0);
      asm("" : "+v"(d2), "+v"(d3));
      #pragma unroll
      for (int j = 0; j < 8; ++j) {
        vacc2[j] = fminf(fminf(vacc2[j], d2[2 * j]), d2[2 * j + 1]);
        vacc3[j] = fminf(fminf(vacc3[j], d3[2 * j]), d3[2 * j + 1]);
      }
    }
  }
  // end-of-wave tree folds (once, amortized over 128 MFMAs/wave)
  float m0, m1, m2, m3;
  {
    float a0 = fminf(fminf(vacc0[0], vacc0[1]), fminf(vacc0[2], vacc0[3]));
    float a1 = fminf(fminf(vacc0[4], vacc0[5]), fminf(vacc0[6], vacc0[7]));
    m0 = fminf(a0, a1);
    float b0 = fminf(fminf(vacc1[0], vacc1[1]), fminf(vacc1[2], vacc1[3]));
    float b1 = fminf(fminf(vacc1[4], vacc1[5]), fminf(vacc1[6], vacc1[7]));
    m1 = fminf(b0, b1);
    float c0 = fminf(fminf(vacc2[0], vacc2[1]), fminf(vacc2[2], vacc2[3]));
    float c1 = fminf(fminf(vacc2[4], vacc2[5]), fminf(vacc2[6], vacc2[7]));
    m2 = fminf(c0, c1);
    float e0 = fminf(fminf(vacc3[0], vacc3[1]), fminf(vacc3[2], vacc3[3]));
    float e1 = fminf(fminf(vacc3[4], vacc3[5]), fminf(vacc3[6], vacc3[7]));
    m3 = fminf(e0, e1);
  }
  // lane^32 holds the other 16 target rows of each tile
  m0 = fminf(m0, __shfl_xor(m0, 32, 64));
  m1 = fminf(m1, __shfl_xor(m1, 32, 64));
  m2 = fminf(m2, __shfl_xor(m2, 32, 64));
  m3 = fminf(m3, __shfl_xor(m3, 32, 64));

  // ---- plain coalesced store of this split's partial mins ----
  if (lane < 32) {
    size_t qi = (size_t)dir * 32768 + (size_t)b * NPTS + qstart + ql;
    float* p = pmin + (size_t)split * NQ_TOT + qi;
    p[0]  = m0;
    p[32] = m1;
    p[64] = m2;
    p[96] = m3;
  }
}

__global__ __launch_bounds__(256) void reduce_kernel(
    const float* __restrict__ pmin, float* __restrict__ out) {
  __shared__ float wsum[4];
  float acc = 0.f;
  for (int i = blockIdx.x * 256 + threadIdx.x; i < NQ_TOT; i += 64 * 256) {
    float v = pmin[i];
    #pragma unroll
    for (int s = 1; s < NSPLIT; ++s) v = fminf(v, pmin[(size_t)s * NQ_TOT + i]);
    acc += fmaxf(v, 0.f);
  }
  acc *= (1.0f / 32768.0f);
  #pragma unroll
  for (int off = 32; off > 0; off >>= 1) acc += __shfl_down(acc, off, 64);
  int wid = threadIdx.x >> 6;
  if ((threadIdx.x & 63) == 0) wsum[wid] = acc;
  __syncthreads();
  if (threadIdx.x == 0) atomicAdd(out, wsum[0] + wsum[1] + wsum[2] + wsum[3]);
}

extern "C" void kernel_launch(void* const* d_in, const int* in_sizes, int n_in,
                              void* d_out, int out_size, void* d_ws, size_t ws_size,
                              hipStream_t stream) {
  const float* pred = (const float*)d_in[0];
  const float* gt   = (const float*)d_in[1];
  float* out = (float*)d_out;
  float* pmin = (float*)d_ws;         // 8 * 65536 * 4 B = 2 MB partial mins

  chamfer_mfma<<<1024, 256, 0, stream>>>(pred, gt, pmin, out);
  reduce_kernel<<<64, 256, 0, stream>>>(pmin, out);
}